// Round 16
// baseline (183.831 us; speedup 1.0000x reference)
//
#include <hip/hip_runtime.h>
#include <math.h>

// Problem constants (B=8, C=192, H=W=32)
#define BB 8
#define CC 192
#define LL 1024
#define RT 8192         // total rows = BB*LL
#define DI 384          // d_inner
#define DT_RANK 12
#define NS 16           // D_STATE
#define NSEG 16
#define SEGL 64

typedef __attribute__((ext_vector_type(8))) short bf16x8;   // 8 bf16 (4 VGPRs)
typedef __attribute__((ext_vector_type(4))) float f32x4;

// RNE float->bf16 and back, manual (no header dependency)
__device__ __forceinline__ unsigned short f2bf(float f) {
    unsigned u = __float_as_uint(f);
    unsigned r = (u + 0x7FFFu + ((u >> 16) & 1u)) >> 16;
    return (unsigned short)r;
}
__device__ __forceinline__ float bf2f(unsigned short h) {
    return __uint_as_float(((unsigned)h) << 16);
}

// row-level DPP shuffle (16-lane rows), compile-time ctrl
#define DPPF(v, ctrl) __int_as_float(__builtin_amdgcn_update_dpp(0, __float_as_int(v), ctrl, 0xF, 0xF, true))

// ---------------------------------------------------------------------------
// K1: W2[j,c'] = sum_c in_proj_w[j,c]*proj_w[c,c'], emitted as SPLIT bf16
// planes W2hi/W2lo (w = hi + lo) for the MFMA gemm_xz. Also splits out_w
// into owhi/owlo planes. bias2[j] = in_proj_w[j,:]·proj_b. Zero-inits xdT.
__global__ void fuse_w_kernel(const float* __restrict__ in_proj_w,
                              const float* __restrict__ proj_w,
                              const float* __restrict__ proj_b,
                              const float* __restrict__ out_w,
                              unsigned short* __restrict__ W2hi,
                              unsigned short* __restrict__ W2lo,
                              unsigned short* __restrict__ owhi,
                              unsigned short* __restrict__ owlo,
                              float* __restrict__ bias2,
                              float* __restrict__ xdT) {
    int j = blockIdx.x;
    int cp = threadIdx.x;
    int gtid = j * CC + cp;                       // 0..147455
    for (int i = gtid; i < 44 * RT; i += 768 * CC) xdT[i] = 0.f;
    if (j < DI) {
        float v = out_w[cp * DI + j];
        unsigned short h = f2bf(v);
        owhi[cp * DI + j] = h;
        owlo[cp * DI + j] = f2bf(v - bf2f(h));
    }
    __shared__ float wrow[CC];
    wrow[cp] = in_proj_w[j * CC + cp];
    __syncthreads();
    float acc = 0.f;
    const float4* wrow4 = (const float4*)wrow;
#pragma unroll 4
    for (int c4 = 0; c4 < CC; c4 += 4) {
        float4 w4 = wrow4[c4 >> 2];
        acc = fmaf(w4.x, proj_w[(c4 + 0) * CC + cp], acc);
        acc = fmaf(w4.y, proj_w[(c4 + 1) * CC + cp], acc);
        acc = fmaf(w4.z, proj_w[(c4 + 2) * CC + cp], acc);
        acc = fmaf(w4.w, proj_w[(c4 + 3) * CC + cp], acc);
    }
    unsigned short h = f2bf(acc);
    W2hi[j * CC + cp] = h;
    W2lo[j * CC + cp] = f2bf(acc - bf2f(h));
    if (cp == 0) {
        float b = 0.f;
        for (int c = 0; c < CC; ++c) b = fmaf(wrow[c], proj_b[c], b);
        bias2[j] = b;
    }
}

// ---------------------------------------------------------------------------
// K2: xzT[j, row] = sum_c x[b,c,l]*W2[j,c] + bias2[j]  via split-bf16 MFMA.
// j-tile 128 (R12-proven). R15: next k-step's 8 x-loads issued right after
// barrier1 (T14) — vmcnt drains at barrier2, AFTER the MFMA phase, hiding
// L2/HBM latency under compute. Pure scheduling: bitwise-identical.
// grid (128,6), 256 thr, 8KB LDS.
__global__ __launch_bounds__(256) void gemm_xz(const float* __restrict__ x,
                                               const unsigned short* __restrict__ W2hi,
                                               const unsigned short* __restrict__ W2lo,
                                               const float* __restrict__ bias2,
                                               float* __restrict__ xzT) {
    __shared__ unsigned short xhi[2048];   // [kb][col][e] 4KB
    __shared__ unsigned short xlo[2048];
    int r0 = blockIdx.x * 64;
    int j0 = blockIdx.y * 128;
    int b  = r0 >> 10;
    int l0 = r0 & 1023;
    int tid = threadIdx.x;
    int lane = tid & 63;
    int wid = tid >> 6;          // wave id = staging kb
    int jw = j0 + wid * 16;      // sub-tile 0; sub-tile 1 at +64
    const float* xb = x + b * CC * LL + l0 + lane;   // staging col = lane
    f32x4 z4 = {0.f, 0.f, 0.f, 0.f};
    f32x4 acc[2][4] = {{z4, z4, z4, z4}, {z4, z4, z4, z4}};
    int arow = lane & 15;                  // A fragment row offset (j)
    int akb  = (lane >> 4) * 8;            // A fragment k sub-block
    float v[8];
#pragma unroll
    for (int e = 0; e < 8; ++e) v[e] = xb[(wid * 8 + e) * LL];
    for (int ks = 0; ks < 6; ++ks) {
        int k0 = ks * 32;
        union U8 { unsigned short u[8]; bf16x8 v8; } hv, lv;
#pragma unroll
        for (int e = 0; e < 8; ++e) {
            unsigned short h = f2bf(v[e]);
            hv.u[e] = h;
            lv.u[e] = f2bf(v[e] - bf2f(h));
        }
        *(bf16x8*)&xhi[(wid * 64 + lane) * 8] = hv.v8;
        *(bf16x8*)&xlo[(wid * 64 + lane) * 8] = lv.v8;
        __syncthreads();
        // T14: issue next k-step's loads now; they drain at barrier2 (under MFMA)
        if (ks < 5) {
#pragma unroll
            for (int e = 0; e < 8; ++e) v[e] = xb[(k0 + 32 + wid * 8 + e) * LL];
        }
        int aoff0 = (jw + arow) * CC + k0 + akb;
        int aoff1 = aoff0 + 64 * CC;
        bf16x8 ah0 = *(const bf16x8*)&W2hi[aoff0];
        bf16x8 al0 = *(const bf16x8*)&W2lo[aoff0];
        bf16x8 ah1 = *(const bf16x8*)&W2hi[aoff1];
        bf16x8 al1 = *(const bf16x8*)&W2lo[aoff1];
#pragma unroll
        for (int rt = 0; rt < 4; ++rt) {
            int boff = ((lane >> 4) * 64 + rt * 16 + (lane & 15)) * 8;
            bf16x8 bh = *(const bf16x8*)&xhi[boff];
            bf16x8 bl = *(const bf16x8*)&xlo[boff];
            acc[0][rt] = __builtin_amdgcn_mfma_f32_16x16x32_bf16(ah0, bh, acc[0][rt], 0, 0, 0);
            acc[0][rt] = __builtin_amdgcn_mfma_f32_16x16x32_bf16(ah0, bl, acc[0][rt], 0, 0, 0);
            acc[0][rt] = __builtin_amdgcn_mfma_f32_16x16x32_bf16(al0, bh, acc[0][rt], 0, 0, 0);
            acc[1][rt] = __builtin_amdgcn_mfma_f32_16x16x32_bf16(ah1, bh, acc[1][rt], 0, 0, 0);
            acc[1][rt] = __builtin_amdgcn_mfma_f32_16x16x32_bf16(ah1, bl, acc[1][rt], 0, 0, 0);
            acc[1][rt] = __builtin_amdgcn_mfma_f32_16x16x32_bf16(al1, bh, acc[1][rt], 0, 0, 0);
        }
        __syncthreads();
    }
    bool is_z = (j0 >= DI);   // j0 in {0,128,256,384,512,640}; DI=384=3*128
#pragma unroll
    for (int js = 0; js < 2; ++js) {
#pragma unroll
        for (int rt = 0; rt < 4; ++rt) {
            int rbase = r0 + rt * 16 + (lane & 15);
#pragma unroll
            for (int reg = 0; reg < 4; ++reg) {
                int j = jw + js * 64 + (lane >> 4) * 4 + reg;
                float o = acc[js][rt][reg] + bias2[j];
                if (is_z) o = __fdividef(o, 1.f + __expf(-o));
                xzT[j * RT + rbase] = o;
            }
        }
    }
}

// ---------------------------------------------------------------------------
// K3: skinny GEMM with fused causal depthwise conv (k=4) + silu in staging.
// 4-way K-split (R11-proven). R15: next k-step's cur/prev/w4/bb prefetched
// after barrier1 (drain at barrier2, hidden under the FMA loop). grid
// (128,4), 512 thr.
__global__ __launch_bounds__(512) void xproj_conv_gemm(const float* __restrict__ xzT,
                                                       const float* __restrict__ conv_w,
                                                       const float* __restrict__ conv_b,
                                                       const float* __restrict__ aw,
                                                       float* __restrict__ xcT,
                                                       float* __restrict__ xdT) {
    __shared__ float Bs[32][64];
    int col0 = blockIdx.x * 64;
    int kbase = blockIdx.y * 96;
    int tid = threadIdx.x;
    int col = tid & 63, mg = tid >> 6;          // mg wave-uniform -> scalar A loads
    int mb = mg * 6;                             // rows mb..mb+5 (44..47 discarded)
    const float* ar[6];
#pragma unroll
    for (int m = 0; m < 6; ++m) ar[m] = aw + min(mb + m, 43) * DI + kbase;
    float acc[6] = {};
    int ks = tid >> 4, c4 = (tid & 15) * 4;
    bool atL0 = ((col0 & 1023) == 0) && (c4 == 0);   // conv zero-pad boundary
    // prefetch k0=0 operands
    int dch = kbase + ks;
    const float* src = xzT + (size_t)dch * RT + col0 + c4;
    float4 cur = *(const float4*)src;
    float4 prev = make_float4(0.f, 0.f, 0.f, 0.f);
    if (!atL0) prev = *(const float4*)(src - 4);
    float4 w4 = *(const float4*)&conv_w[dch * 4];   // w0=x w1=y w2=z w3=w
    float bb = conv_b[dch];
    for (int k0 = 0; k0 < 96; k0 += 32) {
        float v0 = bb + w4.w * cur.x + w4.z * prev.w + w4.y * prev.z + w4.x * prev.y;
        float v1 = bb + w4.w * cur.y + w4.z * cur.x  + w4.y * prev.w + w4.x * prev.z;
        float v2 = bb + w4.w * cur.z + w4.z * cur.y  + w4.y * cur.x  + w4.x * prev.w;
        float v3 = bb + w4.w * cur.w + w4.z * cur.z  + w4.y * cur.y  + w4.x * cur.x;
        float4 o;
        o.x = __fdividef(v0, 1.f + __expf(-v0));
        o.y = __fdividef(v1, 1.f + __expf(-v1));
        o.z = __fdividef(v2, 1.f + __expf(-v2));
        o.w = __fdividef(v3, 1.f + __expf(-v3));
        int dchc = kbase + k0 + ks;
        *(float4*)&Bs[ks][c4] = o;
        *(float4*)&xcT[(size_t)dchc * RT + col0 + c4] = o;   // own channel range
        __syncthreads();
        // T14: prefetch next k-step's operands (drain at barrier2, under FMAs)
        if (k0 < 64) {
            int dchn = kbase + k0 + 32 + ks;
            const float* srcn = xzT + (size_t)dchn * RT + col0 + c4;
            cur = *(const float4*)srcn;
            prev = make_float4(0.f, 0.f, 0.f, 0.f);
            if (!atL0) prev = *(const float4*)(srcn - 4);
            w4 = *(const float4*)&conv_w[dchn * 4];
            bb = conv_b[dchn];
        }
#pragma unroll
        for (int k = 0; k < 32; ++k) {
            float bv = Bs[k][col];
#pragma unroll
            for (int m = 0; m < 6; ++m)
                acc[m] = fmaf(ar[m][k0 + k], bv, acc[m]);
        }
        __syncthreads();
    }
#pragma unroll
    for (int m = 0; m < 6; ++m)
        if (mb + m < 44)
            atomicAdd(&xdT[(mb + m) * RT + col0 + col], acc[m]);
}

// ---------------------------------------------------------------------------
// K4a (R13): per-segment scan from h=0. Whole 64-step segment staged once;
// 2 barriers/block. P/Hf packed into one float2.
// grid (15 seg, 24 dblk, 8 b), block 256.
__global__ __launch_bounds__(256) void scan_part1(const float* __restrict__ xdT,
                                                  const float* __restrict__ xcT,
                                                  const float* __restrict__ dtw,
                                                  const float* __restrict__ dtb,
                                                  const float* __restrict__ A_log,
                                                  float2* __restrict__ PH) {
    __shared__ float dt_s[16][68], g_s[16][68], B_s[16][68];
    __shared__ float dtr_s[12][68];
    __shared__ float dtw_s[192];
    __shared__ float dtb_s[16];
    int seg = blockIdx.x, d0 = blockIdx.y * 16, b = blockIdx.z;
    int row0 = b * LL + seg * SEGL;
    int tid = threadIdx.x;
    int lane = tid & 63;
    int n = lane & 15;
    int dl = ((tid >> 6) << 2) | (lane >> 4);
    int tdd = tid >> 4, ti = tid & 15;
    if (tid < 192) dtw_s[tid] = dtw[d0 * DT_RANK + tid];
    if (tid < 16)  dtb_s[tid] = dtb[d0 + tid];
    float a = -__expf(A_log[(d0 + dl) * NS + n]);
    // ---- stage entire segment (float4-wide)
    *(float4*)&B_s[tdd][ti * 4] = *(const float4*)&xdT[(12 + tdd) * RT + row0 + ti * 4];
    if (tid < 192)
        *(float4*)&dtr_s[tid >> 4][ti * 4] = *(const float4*)&xdT[(tid >> 4) * RT + row0 + ti * 4];
    float4 xv4 = *(const float4*)&xcT[(d0 + tdd) * RT + row0 + ti * 4];
    float xv[4] = {xv4.x, xv4.y, xv4.z, xv4.w};
    __syncthreads();
    // ---- dt compute: 4 cols per thread (same per-col fmaf order as before)
#pragma unroll
    for (int q = 0; q < 4; ++q) {
        int col = ti * 4 + q;
        float acc = dtb_s[tdd];
#pragma unroll
        for (int rr = 0; rr < DT_RANK; ++rr)
            acc = fmaf(dtr_s[rr][col], dtw_s[tdd * DT_RANK + rr], acc);
        float dtv = fmaxf(acc, 0.f) + __logf(1.f + __expf(-fabsf(acc)));
        dt_s[tdd][col] = dtv;
        g_s[tdd][col]  = dtv * xv[q];
    }
    __syncthreads();
    // ---- recurrence, barrier-free
    float h = 0.f, sdt = 0.f;
    for (int ch = 0; ch < 4; ++ch) {
        int c0 = ch * 16;
        float dv[16], gb[16];
#pragma unroll
        for (int q = 0; q < 4; ++q) {
            float4 d4 = *(const float4*)&dt_s[dl][c0 + q * 4];   // row-broadcast
            float4 g4 = *(const float4*)&g_s[dl][c0 + q * 4];
            float4 b4 = *(const float4*)&B_s[n][c0 + q * 4];
            dv[q * 4 + 0] = d4.x; dv[q * 4 + 1] = d4.y;
            dv[q * 4 + 2] = d4.z; dv[q * 4 + 3] = d4.w;
            gb[q * 4 + 0] = g4.x * b4.x; gb[q * 4 + 1] = g4.y * b4.y;
            gb[q * 4 + 2] = g4.z * b4.z; gb[q * 4 + 3] = g4.w * b4.w;
        }
        float eh[16];
#pragma unroll
        for (int i = 0; i < 16; ++i) eh[i] = __expf(dv[i] * a);
#pragma unroll
        for (int i = 0; i < 16; ++i) {
            sdt += dv[i];
            h = fmaf(eh[i], h, gb[i]);
        }
    }
    int idx = ((seg * BB + b) * DI + d0 + dl) * NS + n;
    PH[idx] = make_float2(__expf(a * sdt), h);
}

// ---------------------------------------------------------------------------
// K4b (R13/R14): rescan each segment from folded h_init. Whole-segment
// staging; deferred select-butterfly (bitwise-identical); packed PH fold;
// xr/zr prefetched before the first barrier.
// grid (16 seg, 24 dblk, 8 b), block 256.
__global__ __launch_bounds__(256) void scan_part2(const float* __restrict__ xdT,
                                                  const float* __restrict__ xcT,
                                                  const float* __restrict__ zsT,
                                                  const float* __restrict__ dtw,
                                                  const float* __restrict__ dtb,
                                                  const float2* __restrict__ PH,
                                                  const float* __restrict__ A_log,
                                                  const float* __restrict__ Dp,
                                                  float* __restrict__ yT) {
    __shared__ float dt_s[16][68], g_s[16][68], B_s[16][68], C_s[16][68];
    __shared__ float dtr_s[12][68];
    __shared__ float dtw_s[192];
    __shared__ float dtb_s[16];
    int seg = blockIdx.x, d0 = blockIdx.y * 16, b = blockIdx.z;
    int row0 = b * LL + seg * SEGL;
    int tid = threadIdx.x;
    int lane = tid & 63;
    int n = lane & 15;
    int dl = ((tid >> 6) << 2) | (lane >> 4);
    int d = d0 + dl;
    int tdd = tid >> 4, ti = tid & 15;
    if (tid < 192) dtw_s[tid] = dtw[d0 * DT_RANK + tid];
    if (tid < 16)  dtb_s[tid] = dtb[d0 + tid];
    float a = -__expf(A_log[d * NS + n]);
    float Dpd = Dp[d];
    bool b3 = (n & 8) != 0, b2 = (n & 4) != 0, b1 = (n & 2) != 0, b0 = (n & 1) != 0;
    // ---- stage entire segment (float4-wide)
    *(float4*)&B_s[tdd][ti * 4] = *(const float4*)&xdT[(12 + tdd) * RT + row0 + ti * 4];
    *(float4*)&C_s[tdd][ti * 4] = *(const float4*)&xdT[(28 + tdd) * RT + row0 + ti * 4];
    if (tid < 192)
        *(float4*)&dtr_s[tid >> 4][ti * 4] = *(const float4*)&xdT[(tid >> 4) * RT + row0 + ti * 4];
    float4 xv4 = *(const float4*)&xcT[(d0 + tdd) * RT + row0 + ti * 4];
    float xv[4] = {xv4.x, xv4.y, xv4.z, xv4.w};
    // ---- prefetch epilogue operands for all 4 chunks (writer role (dl,n))
    float xr[4], zr[4];
#pragma unroll
    for (int ch = 0; ch < 4; ++ch) {
        xr[ch] = xcT[(size_t)d * RT + row0 + ch * 16 + n];
        zr[ch] = zsT[(size_t)d * RT + row0 + ch * 16 + n];
    }
    // h_init: fold earlier segments' summaries (packed dwordx2 loads)
    float h = 0.f;
    for (int s = 0; s < seg; ++s) {
        float2 ph = PH[((s * BB + b) * DI + d) * NS + n];
        h = fmaf(ph.x, h, ph.y);
    }
    __syncthreads();
    // ---- dt compute: 4 cols per thread
#pragma unroll
    for (int q = 0; q < 4; ++q) {
        int col = ti * 4 + q;
        float acc = dtb_s[tdd];
#pragma unroll
        for (int rr = 0; rr < DT_RANK; ++rr)
            acc = fmaf(dtr_s[rr][col], dtw_s[tdd * DT_RANK + rr], acc);
        float dtv = fmaxf(acc, 0.f) + __logf(1.f + __expf(-fabsf(acc)));
        dt_s[tdd][col] = dtv;
        g_s[tdd][col]  = dtv * xv[q];
    }
    __syncthreads();
    // ---- recurrence over 4 sub-chunks, barrier-free
    for (int ch = 0; ch < 4; ++ch) {
        int c0 = ch * 16;
        int r = row0 + c0;
        float dv[16], gb[16], cv[16];
#pragma unroll
        for (int q = 0; q < 4; ++q) {
            float4 d4 = *(const float4*)&dt_s[dl][c0 + q * 4];
            float4 g4 = *(const float4*)&g_s[dl][c0 + q * 4];
            float4 b4 = *(const float4*)&B_s[n][c0 + q * 4];
            float4 c4 = *(const float4*)&C_s[n][c0 + q * 4];
            dv[q * 4 + 0] = d4.x; dv[q * 4 + 1] = d4.y;
            dv[q * 4 + 2] = d4.z; dv[q * 4 + 3] = d4.w;
            gb[q * 4 + 0] = g4.x * b4.x; gb[q * 4 + 1] = g4.y * b4.y;
            gb[q * 4 + 2] = g4.z * b4.z; gb[q * 4 + 3] = g4.w * b4.w;
            cv[q * 4 + 0] = c4.x; cv[q * 4 + 1] = c4.y;
            cv[q * 4 + 2] = c4.z; cv[q * 4 + 3] = c4.w;
        }
        float eh[16];
#pragma unroll
        for (int i = 0; i < 16; ++i) eh[i] = __expf(dv[i] * a);
        // recurrence; w[i] = h_after_step_i * C[n][i]
        float w[16];
#pragma unroll
        for (int i = 0; i < 16; ++i) {
            h = fmaf(eh[i], h, gb[i]);
            w[i] = h * cv[i];
        }
        // deferred select-butterfly (R12-proven, bitwise-identical tree)
        float A8[8];
#pragma unroll
        for (int jj = 0; jj < 8; ++jj) {
            float snd = b3 ? w[jj] : w[jj + 8];
            float rcv = DPPF(snd, 0x140);
            A8[jj] = (b3 ? w[jj + 8] : w[jj]) + rcv;
        }
        float A4[4];
#pragma unroll
        for (int jj = 0; jj < 4; ++jj) {
            float snd = b2 ? A8[jj] : A8[jj + 4];
            float rcv = DPPF(snd, 0x141);
            A4[jj] = (b2 ? A8[jj + 4] : A8[jj]) + rcv;
        }
        float A2[2];
#pragma unroll
        for (int jj = 0; jj < 2; ++jj) {
            float s2 = b1 ? A4[jj] : A4[jj + 2];
            float rcv = DPPF(s2, 0x4E);
            A2[jj] = (b1 ? A4[jj + 2] : A4[jj]) + rcv;
        }
        float s1 = b0 ? A2[0] : A2[1];
        float rcv1 = DPPF(s1, 0xB1);
        float yacc = (b0 ? A2[1] : A2[0]) + rcv1;
        yT[(size_t)d * RT + r + n] = fmaf(xr[ch], Dpd, yacc) * zr[ch];
    }
}

// ---------------------------------------------------------------------------
// K5: out[b, c, l] = sum_d yT[d, row] * out_w[c, d]  via split-bf16 MFMA.
// 64-k double staging (R14-proven). R15: next 64-k tile's 16 loads issued
// after barrier1 (drain at barrier2, under the MFMA phase). grid (128, 3),
// 256 thr, 16KB LDS.
__global__ __launch_bounds__(256) void gemm_out(const float* __restrict__ yT,
                                                const unsigned short* __restrict__ owhi,
                                                const unsigned short* __restrict__ owlo,
                                                float* __restrict__ out) {
    __shared__ unsigned short yhi[2][2048];   // [half][kb][col][e] 8KB
    __shared__ unsigned short ylo[2][2048];
    int r0 = blockIdx.x * 64;
    int c0 = blockIdx.y * 64;
    int b  = r0 >> 10;
    int l0 = r0 & 1023;
    int tid = threadIdx.x;
    int lane = tid & 63;
    int wid = tid >> 6;          // wave id = staging kb
    int cw = c0 + wid * 16;
    const float* yb = yT + r0 + lane;      // staging col = lane
    f32x4 z4 = {0.f, 0.f, 0.f, 0.f};
    f32x4 acc[4] = {z4, z4, z4, z4};
    int arow = cw + (lane & 15);           // A fragment row (c)
    int akb  = (lane >> 4) * 8;            // A fragment k sub-block
    float v[2][8];
#pragma unroll
    for (int hh = 0; hh < 2; ++hh)
#pragma unroll
        for (int e = 0; e < 8; ++e)
            v[hh][e] = yb[(size_t)(hh * 32 + wid * 8 + e) * RT];
    for (int ks = 0; ks < 6; ++ks) {
        int k0 = ks * 64;
        union U8 { unsigned short u[8]; bf16x8 v8; } hv, lv;
#pragma unroll
        for (int hh = 0; hh < 2; ++hh) {
#pragma unroll
            for (int e = 0; e < 8; ++e) {
                unsigned short hb = f2bf(v[hh][e]);
                hv.u[e] = hb;
                lv.u[e] = f2bf(v[hh][e] - bf2f(hb));
            }
            *(bf16x8*)&yhi[hh][(wid * 64 + lane) * 8] = hv.v8;
            *(bf16x8*)&ylo[hh][(wid * 64 + lane) * 8] = lv.v8;
        }
        __syncthreads();
        // T14: issue next tile's loads now; drain at barrier2 (under MFMA)
        if (ks < 5) {
#pragma unroll
            for (int hh = 0; hh < 2; ++hh)
#pragma unroll
                for (int e = 0; e < 8; ++e)
                    v[hh][e] = yb[(size_t)(k0 + 64 + hh * 32 + wid * 8 + e) * RT];
        }
#pragma unroll
        for (int hh = 0; hh < 2; ++hh) {
            int aoff = arow * DI + k0 + hh * 32 + akb;
            bf16x8 ah = *(const bf16x8*)&owhi[aoff];
            bf16x8 al = *(const bf16x8*)&owlo[aoff];
#pragma unroll
            for (int rt = 0; rt < 4; ++rt) {
                int boff = ((lane >> 4) * 64 + rt * 16 + (lane & 15)) * 8;
                bf16x8 bh = *(const bf16x8*)&yhi[hh][boff];
                bf16x8 bl = *(const bf16x8*)&ylo[hh][boff];
                acc[rt] = __builtin_amdgcn_mfma_f32_16x16x32_bf16(ah, bh, acc[rt], 0, 0, 0);
                acc[rt] = __builtin_amdgcn_mfma_f32_16x16x32_bf16(ah, bl, acc[rt], 0, 0, 0);
                acc[rt] = __builtin_amdgcn_mfma_f32_16x16x32_bf16(al, bh, acc[rt], 0, 0, 0);
            }
        }
        __syncthreads();
    }
    float* ob = out + b * CC * LL;
#pragma unroll
    for (int rt = 0; rt < 4; ++rt) {
        int lbase = l0 + rt * 16 + (lane & 15);
#pragma unroll
        for (int reg = 0; reg < 4; ++reg) {
            int c = cw + (lane >> 4) * 4 + reg;
            ob[c * LL + lbase] = acc[rt][reg];
        }
    }
}

// ---------------------------------------------------------------------------
extern "C" void kernel_launch(void* const* d_in, const int* in_sizes, int n_in,
                              void* d_out, int out_size, void* d_ws, size_t ws_size,
                              hipStream_t stream) {
    const float* x         = (const float*)d_in[0];
    const float* proj_w    = (const float*)d_in[1];
    const float* proj_b    = (const float*)d_in[2];
    const float* in_proj_w = (const float*)d_in[3];
    const float* conv_w    = (const float*)d_in[4];
    const float* conv_b    = (const float*)d_in[5];
    const float* xproj_w   = (const float*)d_in[6];
    const float* dtproj_w  = (const float*)d_in[7];
    const float* dtproj_b  = (const float*)d_in[8];
    const float* A_log     = (const float*)d_in[9];
    const float* Dp        = (const float*)d_in[10];
    const float* out_w     = (const float*)d_in[11];
    float* out = (float*)d_out;

    float* ws    = (float*)d_ws;
    unsigned short* W2hi = (unsigned short*)ws;          // 147456 bf16 = 73728 f32 slots
    unsigned short* W2lo = (unsigned short*)(ws + 73728);
    float* bias2 = ws + 147456;           // 768
    float* xzT   = bias2 + 768;           // 768*8192 = 6291456 (x raw, z silu'd)
    float* xcT   = xzT + 6291456;         // 3145728
    float* yT    = xcT + 3145728;         // 3145728
    float* xdT   = yT + 3145728;          // 44*8192 = 360448 (0-11 dtr, 12-27 B, 28-43 C)
    float2* PH   = (float2*)(xdT + 360448);              // 786432 float2 (8B-aligned)
    unsigned short* owhi = (unsigned short*)(xdT + 360448 + 1572864);  // 73728 bf16
    unsigned short* owlo = (unsigned short*)(xdT + 360448 + 1572864 + 36864);
    float* zsT   = xzT + DI * RT;         // z half, silu applied by gemm_xz epilogue

    fuse_w_kernel<<<768, 192, 0, stream>>>(in_proj_w, proj_w, proj_b, out_w,
                                           W2hi, W2lo, owhi, owlo, bias2, xdT);
    gemm_xz<<<dim3(128, 6), 256, 0, stream>>>(x, W2hi, W2lo, bias2, xzT);
    xproj_conv_gemm<<<dim3(128, 4), 512, 0, stream>>>(xzT, conv_w, conv_b,
                                                      xproj_w, xcT, xdT);
    scan_part1<<<dim3(15, 24, 8), 256, 0, stream>>>(xdT, xcT, dtproj_w, dtproj_b,
                                                    A_log, PH);
    scan_part2<<<dim3(16, 24, 8), 256, 0, stream>>>(xdT, xcT, zsT, dtproj_w, dtproj_b,
                                                    PH, A_log, Dp, yT);
    gemm_out<<<dim3(128, 3), 256, 0, stream>>>(yT, owhi, owlo, out);
}